// Round 1
// baseline (44.239 us; speedup 1.0000x reference)
//
#include <hip/hip_runtime.h>
#include <hip/hip_bf16.h>

constexpr int L_LEN = 4096;
constexpr int CH = 8;          // channels
constexpr int S_SAMPLES = 256; // continuous start samples
constexpr int K_SAMP = 32;     // shapelet samples
constexpr int NSHAPE = 16;
constexpr int NB = 32;         // batch
constexpr int P_PER_BLOCK = 4;
constexpr int THREADS = NB * P_PER_BLOCK; // 128

// Compute integral(b, s, p) and atomically min-reduce over p into ws_min[s*NB+b]
__global__ __launch_bounds__(THREADS) void shapelet_min_kernel(
    const float* __restrict__ path,      // (B, L, C)
    const float* __restrict__ lengths,   // (NSHAPE)
    const float* __restrict__ shapelets, // (NSHAPE, K, C)
    unsigned int* __restrict__ ws_min)   // (NSHAPE, NB) float-as-uint
{
    __shared__ float sh[K_SAMP * CH];     // 1 KB, this block's shapelet
    __shared__ float red[P_PER_BLOCK][NB];

    const int s   = blockIdx.y;
    const int tid = threadIdx.x;
    const int b   = tid & (NB - 1);
    const int pl  = tid >> 5;                       // 0..3
    const int p   = blockIdx.x * P_PER_BLOCK + pl;  // 0..255

    for (int i = tid; i < K_SAMP * CH; i += THREADS)
        sh[i] = shapelets[s * K_SAMP * CH + i];
    __syncthreads();

    const float len = fminf(fmaxf(lengths[s], 0.01f), 512.0f);
    const float tN  = (float)(L_LEN - 1);
    const float start = ((float)p / (float)(S_SAMPLES - 1)) * (tN - len);

    // path rows for batch b, as float4 (C=8 -> 2 float4 per row)
    const float4* __restrict__ prow =
        reinterpret_cast<const float4*>(path) + (size_t)b * (L_LEN * (CH / 4));

    float sumsq = 0.f, cross = 0.f, sq_first = 0.f, sq_last = 0.f;
    float dprev[CH];
    #pragma unroll
    for (int c = 0; c < CH; ++c) dprev[c] = 0.f;

    #pragma unroll 4
    for (int k = 0; k < K_SAMP; ++k) {
        const float unit = (float)k / (float)(K_SAMP - 1);
        const float q = start + unit * len;
        int idx = (int)floorf(q);
        idx = min(max(idx, 0), L_LEN - 2);
        const float r = q - (float)idx;

        // rows idx and idx+1 are contiguous: 64B
        const float4 a0 = prow[idx * 2 + 0];
        const float4 a1 = prow[idx * 2 + 1];
        const float4 c0 = prow[idx * 2 + 2];
        const float4 c1 = prow[idx * 2 + 3];

        const float pv[CH] = {a0.x, a0.y, a0.z, a0.w, a1.x, a1.y, a1.z, a1.w};
        const float nv[CH] = {c0.x, c0.y, c0.z, c0.w, c1.x, c1.y, c1.z, c1.w};

        float d[CH];
        float sq = 0.f, cr = 0.f;
        #pragma unroll
        for (int c = 0; c < CH; ++c) {
            const float samp = pv[c] + r * (nv[c] - pv[c]);
            d[c] = samp - sh[k * CH + c];
            sq += d[c] * d[c];
            cr += dprev[c] * d[c];
        }
        sumsq += sq;
        if (k > 0) cross += cr;
        if (k == 0) sq_first = sq;
        sq_last = sq;
        #pragma unroll
        for (int c = 0; c < CH; ++c) dprev[c] = d[c];
    }

    // integral = dt/3 * (2*sumsq - sq_first - sq_last + cross), dt = len/(K-1)
    float integral = (len * (1.0f / (float)(K_SAMP - 1))) * (1.0f / 3.0f) *
                     (2.f * sumsq - sq_first - sq_last + cross);
    integral = fmaxf(integral, 0.0f); // keep uint-min ordering valid

    red[pl][b] = integral;
    __syncthreads();
    if (tid < NB) {
        float m = red[0][b];
        #pragma unroll
        for (int j = 1; j < P_PER_BLOCK; ++j) m = fminf(m, red[j][b]);
        atomicMin(ws_min + s * NB + b, __float_as_uint(m));
    }
}

__global__ void shapelet_finalize_kernel(const unsigned int* __restrict__ ws_min,
                                         float* __restrict__ out)
{
    const int i = threadIdx.x + blockIdx.x * blockDim.x;
    if (i < NSHAPE * NB) {
        const int s = i / NB;
        const int b = i % NB;
        const float v = __uint_as_float(ws_min[i]);
        out[b * NSHAPE + s] = sqrtf(fmaxf(v, 1e-12f));
    }
}

extern "C" void kernel_launch(void* const* d_in, const int* in_sizes, int n_in,
                              void* d_out, int out_size, void* d_ws, size_t ws_size,
                              hipStream_t stream) {
    // inputs: times (L), path (B,L,C), lengths (NSHAPE), shapelets (NSHAPE,K,C)
    const float* path      = (const float*)d_in[1];
    const float* lengths   = (const float*)d_in[2];
    const float* shapelets = (const float*)d_in[3];
    float* out = (float*)d_out;
    unsigned int* ws_min = (unsigned int*)d_ws;

    // init mins to huge float (0x7f7f7f7f ~ 3.39e38), deterministic each call
    hipMemsetAsync(ws_min, 0x7f, NSHAPE * NB * sizeof(unsigned int), stream);

    dim3 grid(S_SAMPLES / P_PER_BLOCK, NSHAPE);
    shapelet_min_kernel<<<grid, THREADS, 0, stream>>>(path, lengths, shapelets, ws_min);
    shapelet_finalize_kernel<<<1, NSHAPE * NB, 0, stream>>>(ws_min, out);
}